// Round 2
// baseline (999.372 us; speedup 1.0000x reference)
//
#include <hip/hip_runtime.h>
#include <hip/hip_bf16.h>

#define CIN  32
#define COUT 64
#define KVOL 27
#define KCEN 13
#define FEPS 1e-5f
#define SEGCAP 32768

// ws layout (4-byte units):
// [0,32)    channel sums
// [32,64)   channel sums of squares
// [64,96)   scale[c]
// [96,128)  bias[c]
// [128,160) cnt[27] pair counters (int) + pad
// [160, 160+N*16)            xhat, bf16-packed: 16 u32 words per row (32 ch)
// [160+N*16, +27*SEGCAP*2)   pair segments: int2 seg[27][SEGCAP] = (src, dst)

__device__ __forceinline__ unsigned bfr(float f) {   // f32 -> bf16 bits, RNE
    unsigned u = __float_as_uint(f);
    return (u + 0x7FFFu + ((u >> 16) & 1u)) >> 16;
}

// unpack word t (2 channels) and fma into acc; even c = low half, odd = high half
#define FMA2(u, c, acc)                                                   \
    acc = fmaf(__uint_as_float((u) << 16), w[(c)], acc);                  \
    acc = fmaf(__uint_as_float((u) & 0xFFFF0000u), w[(c) + 1], acc);

// dot of one packed row (4x uint4 = 32 bf16) with w[0..31]; 2 chains to cut dep latency
#define DOT(q0, q1, q2, q3, acc)                                          \
    {                                                                     \
        float accA = 0.f, accB = 0.f;                                     \
        FMA2(q0.x, 0, accA)  FMA2(q0.y, 2, accA)                          \
        FMA2(q0.z, 4, accA)  FMA2(q0.w, 6, accA)                          \
        FMA2(q1.x, 8, accA)  FMA2(q1.y, 10, accA)                         \
        FMA2(q1.z, 12, accA) FMA2(q1.w, 14, accA)                         \
        FMA2(q2.x, 16, accB) FMA2(q2.y, 18, accB)                         \
        FMA2(q2.z, 20, accB) FMA2(q2.w, 22, accB)                         \
        FMA2(q3.x, 24, accB) FMA2(q3.y, 26, accB)                         \
        FMA2(q3.z, 28, accB) FMA2(q3.w, 30, accB)                         \
        acc = accA + accB;                                                \
    }

__global__ void k_zero(float* __restrict__ ws) {
    if (threadIdx.x < 160) ws[threadIdx.x] = 0.f;
}

__global__ __launch_bounds__(256) void k_reduce(const float* __restrict__ f,
                                                float* __restrict__ ws, int n4) {
    const float4* f4 = (const float4*)f;
    int tid    = blockIdx.x * blockDim.x + threadIdx.x;
    int stride = gridDim.x * blockDim.x;          // multiple of 8
    float4 s = make_float4(0.f, 0.f, 0.f, 0.f);
    float4 q = make_float4(0.f, 0.f, 0.f, 0.f);
    for (int i = tid; i < n4; i += stride) {
        float4 v = f4[i];
        s.x += v.x; s.y += v.y; s.z += v.z; s.w += v.w;
        q.x = fmaf(v.x, v.x, q.x); q.y = fmaf(v.y, v.y, q.y);
        q.z = fmaf(v.z, v.z, q.z); q.w = fmaf(v.w, v.w, q.w);
    }
    __shared__ float ls[64];
    if (threadIdx.x < 64) ls[threadIdx.x] = 0.f;
    __syncthreads();
    int g = threadIdx.x & 7;
    atomicAdd(&ls[g * 4 + 0], s.x); atomicAdd(&ls[g * 4 + 1], s.y);
    atomicAdd(&ls[g * 4 + 2], s.z); atomicAdd(&ls[g * 4 + 3], s.w);
    atomicAdd(&ls[32 + g * 4 + 0], q.x); atomicAdd(&ls[32 + g * 4 + 1], q.y);
    atomicAdd(&ls[32 + g * 4 + 2], q.z); atomicAdd(&ls[32 + g * 4 + 3], q.w);
    __syncthreads();
    if (threadIdx.x < 64) atomicAdd(&ws[threadIdx.x], ls[threadIdx.x]);
}

__global__ void k_final(const float* __restrict__ gamma, const float* __restrict__ beta,
                        float* __restrict__ ws, float invN) {
    int c = threadIdx.x;                          // 32 threads
    float mean = ws[c] * invN;
    float var  = fmaf(-mean, mean, ws[32 + c] * invN);
    float sc   = gamma[c] * rsqrtf(var + FEPS);
    ws[64 + c] = sc;
    ws[96 + c] = fmaf(-mean, sc, beta[c]);
}

// xhat = relu(f*scale+bias), packed to bf16 pairs. float4 in -> uint2 out.
__global__ __launch_bounds__(256) void k_norm(const float* __restrict__ f,
                                              const float* __restrict__ ws,
                                              unsigned* __restrict__ xb, int n4) {
    const float4* f4 = (const float4*)f;
    uint2* o = (uint2*)xb;
    int tid    = blockIdx.x * blockDim.x + threadIdx.x;
    int stride = gridDim.x * blockDim.x;          // multiple of 8
    int g = threadIdx.x & 7;
    float4 sc = ((const float4*)(ws + 64))[g];
    float4 bi = ((const float4*)(ws + 96))[g];
    for (int i = tid; i < n4; i += stride) {
        float4 v = f4[i];
        v.x = fmaxf(fmaf(v.x, sc.x, bi.x), 0.f);
        v.y = fmaxf(fmaf(v.y, sc.y, bi.y), 0.f);
        v.z = fmaxf(fmaf(v.z, sc.z, bi.z), 0.f);
        v.w = fmaxf(fmaf(v.w, sc.w, bi.w), 0.f);
        uint2 r;
        r.x = (bfr(v.y) << 16) | bfr(v.x);
        r.y = (bfr(v.w) << 16) | bfr(v.z);
        o[i] = r;
    }
}

// Build dense (src,dst) pair lists per non-center offset.
__global__ __launch_bounds__(256) void k_compact(const int* __restrict__ nbr,
                                                 int* __restrict__ cnt,
                                                 int2* __restrict__ seg, int n) {
    int lane = threadIdx.x;
    int k = blockIdx.y; if (k >= KCEN) ++k;
    const int*  nk  = nbr + (size_t)k * n;
    const int4* nk4 = (const int4*)nk;
    int2* sg = seg + (size_t)k * SEGCAP;
    int wid   = __builtin_amdgcn_readfirstlane(blockIdx.x * 4 + threadIdx.y);
    int waves = gridDim.x * 4;
    int nch   = n >> 8;                            // full 256-voxel chunks
    for (int ch = wid; ch < nch; ch += waves) {
        int4 v = nk4[ch * 64 + lane];
#pragma unroll
        for (int j = 0; j < 4; ++j) {
            int idx = (j == 0) ? v.x : (j == 1) ? v.y : (j == 2) ? v.z : v.w;
            unsigned long long m = __ballot(idx >= 0);
            if (m) {
                int base = 0;
                if (lane == 0) base = atomicAdd(&cnt[k], __popcll(m));
                base = __shfl(base, 0);
                if (idx >= 0) {
                    int pos = base + __popcll(m & ((1ull << lane) - 1));
                    if (pos < SEGCAP)
                        sg[pos] = make_int2(idx, ch * 256 + 4 * lane + j);
                }
            }
        }
    }
    // remainder (n % 256 voxels), handled by wave 0 of each k
    if (wid == 0) {
        int nfull = nch << 8;
        for (int i0 = nfull; i0 < n; i0 += 64) {
            int i = i0 + lane;
            int idx = (i < n) ? nk[i] : -1;
            unsigned long long m = __ballot(idx >= 0);
            if (m) {
                int base = 0;
                if (lane == 0) base = atomicAdd(&cnt[k], __popcll(m));
                base = __shfl(base, 0);
                if (idx >= 0) {
                    int pos = base + __popcll(m & ((1ull << lane) - 1));
                    if (pos < SEGCAP) sg[pos] = make_int2(idx, i);
                }
            }
        }
    }
}

// Dense center pass (k=13, src==dst): batched 4 voxels, plain stores init out.
__global__ __launch_bounds__(256) void k_center(const unsigned* __restrict__ xb,
                                                const float* __restrict__ W,
                                                float* __restrict__ out, int n) {
    int lane = threadIdx.x;
    float w[CIN];
#pragma unroll
    for (int c = 0; c < CIN; ++c) w[c] = W[(size_t)KCEN * (CIN * COUT) + c * COUT + lane];
    int wid   = __builtin_amdgcn_readfirstlane(blockIdx.x * 4 + threadIdx.y);
    int waves = gridDim.x * 4;
    int nb = n >> 2;                               // n % 4 == 0
    for (int b = wid; b < nb; b += waves) {
        int i = b * 4;
        const uint4* r0 = (const uint4*)(xb + (size_t)(i + 0) * 16);
        const uint4* r1 = (const uint4*)(xb + (size_t)(i + 1) * 16);
        const uint4* r2 = (const uint4*)(xb + (size_t)(i + 2) * 16);
        const uint4* r3 = (const uint4*)(xb + (size_t)(i + 3) * 16);
        uint4 a0 = r0[0], b0 = r0[1], c0 = r0[2], d0 = r0[3];
        uint4 a1 = r1[0], b1 = r1[1], c1 = r1[2], d1 = r1[3];
        uint4 a2 = r2[0], b2 = r2[1], c2 = r2[2], d2 = r2[3];
        uint4 a3 = r3[0], b3 = r3[1], c3 = r3[2], d3 = r3[3];
        float s0, s1, s2, s3;
        DOT(a0, b0, c0, d0, s0)
        DOT(a1, b1, c1, d1, s1)
        DOT(a2, b2, c2, d2, s2)
        DOT(a3, b3, c3, d3, s3)
        out[(size_t)(i + 0) * COUT + lane] = s0;
        out[(size_t)(i + 1) * COUT + lane] = s1;
        out[(size_t)(i + 2) * COUT + lane] = s2;
        out[(size_t)(i + 3) * COUT + lane] = s3;
    }
}

// Pair GEMV: per offset k, wave strides over dense pair list, 4 pairs in flight.
__global__ __launch_bounds__(256) void k_pairs(const unsigned* __restrict__ xb,
                                               const float* __restrict__ W,
                                               const int* __restrict__ cnt,
                                               const int2* __restrict__ seg,
                                               float* __restrict__ out) {
    int lane = threadIdx.x;
    int k = blockIdx.y; if (k >= KCEN) ++k;
    float w[CIN];
#pragma unroll
    for (int c = 0; c < CIN; ++c) w[c] = W[(size_t)k * (CIN * COUT) + c * COUT + lane];
    int nc = cnt[k]; if (nc > SEGCAP) nc = SEGCAP;
    const int2* sg = seg + (size_t)k * SEGCAP;
    int wid   = __builtin_amdgcn_readfirstlane(blockIdx.x * 4 + threadIdx.y);
    int waves = gridDim.x * 4;
    int nb = nc >> 2;
    for (int b = wid; b < nb; b += waves) {
        int j = b * 4;
        int2 p0 = sg[j], p1 = sg[j + 1], p2 = sg[j + 2], p3 = sg[j + 3];
        int s0 = __builtin_amdgcn_readfirstlane(p0.x), d0i = __builtin_amdgcn_readfirstlane(p0.y);
        int s1 = __builtin_amdgcn_readfirstlane(p1.x), d1i = __builtin_amdgcn_readfirstlane(p1.y);
        int s2 = __builtin_amdgcn_readfirstlane(p2.x), d2i = __builtin_amdgcn_readfirstlane(p2.y);
        int s3 = __builtin_amdgcn_readfirstlane(p3.x), d3i = __builtin_amdgcn_readfirstlane(p3.y);
        const uint4* r0 = (const uint4*)(xb + (size_t)s0 * 16);
        const uint4* r1 = (const uint4*)(xb + (size_t)s1 * 16);
        const uint4* r2 = (const uint4*)(xb + (size_t)s2 * 16);
        const uint4* r3 = (const uint4*)(xb + (size_t)s3 * 16);
        uint4 a0 = r0[0], b0 = r0[1], c0 = r0[2], d0 = r0[3];
        uint4 a1 = r1[0], b1 = r1[1], c1 = r1[2], d1 = r1[3];
        uint4 a2 = r2[0], b2 = r2[1], c2 = r2[2], d2 = r2[3];
        uint4 a3 = r3[0], b3 = r3[1], c3 = r3[2], d3 = r3[3];
        float t0, t1, t2, t3;
        DOT(a0, b0, c0, d0, t0)
        DOT(a1, b1, c1, d1, t1)
        DOT(a2, b2, c2, d2, t2)
        DOT(a3, b3, c3, d3, t3)
        unsafeAtomicAdd(&out[(size_t)d0i * COUT + lane], t0);
        unsafeAtomicAdd(&out[(size_t)d1i * COUT + lane], t1);
        unsafeAtomicAdd(&out[(size_t)d2i * COUT + lane], t2);
        unsafeAtomicAdd(&out[(size_t)d3i * COUT + lane], t3);
    }
    // tail (nc % 4), one wave per k
    if (wid == 0) {
        for (int j = nb * 4; j < nc; ++j) {
            int2 p = sg[j];
            int s = __builtin_amdgcn_readfirstlane(p.x);
            int d = __builtin_amdgcn_readfirstlane(p.y);
            const uint4* r = (const uint4*)(xb + (size_t)s * 16);
            uint4 a = r[0], b = r[1], c = r[2], e = r[3];
            float t;
            DOT(a, b, c, e, t)
            unsafeAtomicAdd(&out[(size_t)d * COUT + lane], t);
        }
    }
}

extern "C" void kernel_launch(void* const* d_in, const int* in_sizes, int n_in,
                              void* d_out, int out_size, void* d_ws, size_t ws_size,
                              hipStream_t stream) {
    const float* feat  = (const float*)d_in[0];
    const float* gamma = (const float*)d_in[1];
    const float* beta  = (const float*)d_in[2];
    const float* W     = (const float*)d_in[3];
    const int*   nbr   = (const int*)d_in[4];
    float* out = (float*)d_out;
    float* ws  = (float*)d_ws;

    int n  = in_sizes[0] / CIN;                    // 400000
    int n4 = in_sizes[0] / 4;
    unsigned* xb  = (unsigned*)(ws + 160);
    int*      cnt = (int*)(ws + 128);
    int2*     seg = (int2*)(ws + 160 + (size_t)n * 16);

    hipLaunchKernelGGL(k_zero,    dim3(1), dim3(256), 0, stream, ws);
    hipLaunchKernelGGL(k_compact, dim3(32, 26), dim3(64, 4), 0, stream, nbr, cnt, seg, n);
    hipLaunchKernelGGL(k_reduce,  dim3(512), dim3(256), 0, stream, feat, ws, n4);
    hipLaunchKernelGGL(k_final,   dim3(1), dim3(32), 0, stream, gamma, beta, ws, 1.0f / (float)n);
    hipLaunchKernelGGL(k_norm,    dim3(2048), dim3(256), 0, stream, feat, ws, xb, n4);
    hipLaunchKernelGGL(k_center,  dim3(1024), dim3(64, 4), 0, stream, xb, W, out, n);
    hipLaunchKernelGGL(k_pairs,   dim3(20, 26), dim3(64, 4), 0, stream, xb, W, cnt, seg, out);
}

// Round 3
// 344.718 us; speedup vs baseline: 2.8991x; 2.8991x over previous
//
#include <hip/hip_runtime.h>
#include <hip/hip_bf16.h>

#define CIN    32
#define COUT   64
#define KVOL   27
#define KCEN   13
#define FEPS   1e-5f
#define STILE  384          // voxels per subtile
#define LPAD   68           // padded row stride (floats) for LDS acc
#define NWAVE  16           // waves per block (1024 threads)

// ws float layout:
// [0,32)   channel sums        [32,64)  channel sumsq
// [64,96)  scale[c]            [96,128) bias[c]
// [144]    ticket counter (int)
// [160,160+N*32) xhat f32 [N][32]

__global__ void k_zero(float* __restrict__ ws) {
    if (threadIdx.x < 160) ws[threadIdx.x] = 0.f;
}

__global__ __launch_bounds__(256) void k_reduce(const float* __restrict__ f,
                                                float* __restrict__ ws, int n4) {
    const float4* f4 = (const float4*)f;
    int tid    = blockIdx.x * blockDim.x + threadIdx.x;
    int stride = gridDim.x * blockDim.x;          // multiple of 8
    float4 s = make_float4(0.f, 0.f, 0.f, 0.f);
    float4 q = make_float4(0.f, 0.f, 0.f, 0.f);
    for (int i = tid; i < n4; i += stride) {
        float4 v = f4[i];
        s.x += v.x; s.y += v.y; s.z += v.z; s.w += v.w;
        q.x = fmaf(v.x, v.x, q.x); q.y = fmaf(v.y, v.y, q.y);
        q.z = fmaf(v.z, v.z, q.z); q.w = fmaf(v.w, v.w, q.w);
    }
    __shared__ float ls[64];
    if (threadIdx.x < 64) ls[threadIdx.x] = 0.f;
    __syncthreads();
    int g = threadIdx.x & 7;
    atomicAdd(&ls[g * 4 + 0], s.x); atomicAdd(&ls[g * 4 + 1], s.y);
    atomicAdd(&ls[g * 4 + 2], s.z); atomicAdd(&ls[g * 4 + 3], s.w);
    atomicAdd(&ls[32 + g * 4 + 0], q.x); atomicAdd(&ls[32 + g * 4 + 1], q.y);
    atomicAdd(&ls[32 + g * 4 + 2], q.z); atomicAdd(&ls[32 + g * 4 + 3], q.w);
    __syncthreads();
    if (threadIdx.x < 64) atomicAdd(&ws[threadIdx.x], ls[threadIdx.x]);
}

__global__ void k_final(const float* __restrict__ gamma, const float* __restrict__ beta,
                        float* __restrict__ ws, float invN) {
    int c = threadIdx.x;                          // 32 threads
    float mean = ws[c] * invN;
    float var  = fmaf(-mean, mean, ws[32 + c] * invN);
    float sc   = gamma[c] * rsqrtf(var + FEPS);
    ws[64 + c] = sc;
    ws[96 + c] = fmaf(-mean, sc, beta[c]);
}

__global__ __launch_bounds__(256) void k_norm(const float* __restrict__ f,
                                              const float* __restrict__ ws,
                                              float* __restrict__ xh, int n4) {
    const float4* f4 = (const float4*)f;
    float4* o4 = (float4*)xh;
    int tid    = blockIdx.x * blockDim.x + threadIdx.x;
    int stride = gridDim.x * blockDim.x;          // multiple of 8
    int g = threadIdx.x & 7;
    float4 sc = ((const float4*)(ws + 64))[g];
    float4 bi = ((const float4*)(ws + 96))[g];
    for (int i = tid; i < n4; i += stride) {
        float4 v = f4[i];
        v.x = fmaxf(fmaf(v.x, sc.x, bi.x), 0.f);
        v.y = fmaxf(fmaf(v.y, sc.y, bi.y), 0.f);
        v.z = fmaxf(fmaf(v.z, sc.z, bi.z), 0.f);
        v.w = fmaxf(fmaf(v.w, sc.w, bi.w), 0.f);
        o4[i] = v;
    }
}

// gather one xhat row (uniform address -> scalar loads) and dot with w[0..31]
__device__ __forceinline__ float rowdot(const float* __restrict__ xh, int src,
                                        const float* w) {
    const float4* xr = (const float4*)(xh + (size_t)src * CIN);
    float4 x0 = xr[0], x1 = xr[1], x2 = xr[2], x3 = xr[3];
    float4 x4 = xr[4], x5 = xr[5], x6 = xr[6], x7 = xr[7];
    float a = 0.f, b = 0.f, c = 0.f, d = 0.f;
    a = fmaf(x0.x, w[0], a);  b = fmaf(x0.y, w[1], b);
    c = fmaf(x0.z, w[2], c);  d = fmaf(x0.w, w[3], d);
    a = fmaf(x1.x, w[4], a);  b = fmaf(x1.y, w[5], b);
    c = fmaf(x1.z, w[6], c);  d = fmaf(x1.w, w[7], d);
    a = fmaf(x2.x, w[8], a);  b = fmaf(x2.y, w[9], b);
    c = fmaf(x2.z, w[10], c); d = fmaf(x2.w, w[11], d);
    a = fmaf(x3.x, w[12], a); b = fmaf(x3.y, w[13], b);
    c = fmaf(x3.z, w[14], c); d = fmaf(x3.w, w[15], d);
    a = fmaf(x4.x, w[16], a); b = fmaf(x4.y, w[17], b);
    c = fmaf(x4.z, w[18], c); d = fmaf(x4.w, w[19], d);
    a = fmaf(x5.x, w[20], a); b = fmaf(x5.y, w[21], b);
    c = fmaf(x5.z, w[22], c); d = fmaf(x5.w, w[23], d);
    a = fmaf(x6.x, w[24], a); b = fmaf(x6.y, w[25], b);
    c = fmaf(x6.z, w[26], c); d = fmaf(x6.w, w[27], d);
    a = fmaf(x7.x, w[28], a); b = fmaf(x7.y, w[29], b);
    c = fmaf(x7.z, w[30], c); d = fmaf(x7.w, w[31], d);
    return (a + b) + (c + d);
}

// Gather-form sparse conv. Persistent blocks, ticket-dispatched 384-voxel
// subtiles, LDS f32 accumulators (ds_add_f32 takes runtime addresses -> no
// register-indexing spill), out written once with plain coalesced stores.
__global__ __launch_bounds__(1024) void k_conv(const float* __restrict__ xh,
                                               const float* __restrict__ W,
                                               const int* __restrict__ nbr,
                                               float* __restrict__ out,
                                               int* __restrict__ tick,
                                               int n, int nsub) {
    __shared__ float acc[STILE * LPAD];            // 104448 B
    __shared__ int st_sh;

    int lane = threadIdx.x & 63;
    int w    = threadIdx.x >> 6;                   // wave id 0..15

    // center weight column resident for the whole block lifetime
    float w13[CIN];
#pragma unroll
    for (int c = 0; c < CIN; ++c) w13[c] = W[(size_t)KCEN * (CIN * COUT) + c * COUT + lane];

    // sparse-k assignment: j in {w, w+16} (j<26), k = j + (j>=13)
    int j0 = w;
    int j1 = (w + NWAVE < 26) ? (w + NWAVE) : -1;

    for (;;) {
        if (threadIdx.x == 0) st_sh = atomicAdd(tick, 1);
        __syncthreads();
        int st = st_sh;
        if (st >= nsub) break;
        int st0  = st * STILE;
        int nvox = min(STILE, n - st0);            // multiple of 64

        // zero accumulators
        for (int t = threadIdx.x; t < STILE * LPAD; t += 1024) acc[t] = 0.f;
        __syncthreads();

        // ---- center pass: wave w owns voxels [24w, 24w+24) of subtile ----
        {
            int vv   = 24 * w + lane;              // lanes 0..23 carry idx
            int cidx = (lane < 24 && 24 * w + lane < nvox)
                           ? nbr[(size_t)KCEN * n + st0 + vv] : -1;
#pragma unroll 4
            for (int j = 0; j < 24; ++j) {
                int v = 24 * w + j;
                if (v >= nvox) break;              // wave-uniform
                int src = __builtin_amdgcn_readlane(cidx, j);
                if (src >= 0) {
                    float t = rowdot(xh, src, w13);
                    atomicAdd(&acc[v * LPAD + lane], t);
                }
            }
        }

        // ---- sparse pass: ballot-peel, W column amortized over subtile ----
        for (int jj = 0; jj < 2; ++jj) {
            int j = (jj == 0) ? j0 : j1;
            if (j < 0 || j >= 26) continue;
            int k = j + (j >= KCEN);
            float wk[CIN];
#pragma unroll
            for (int c = 0; c < CIN; ++c) wk[c] = W[(size_t)k * (CIN * COUT) + c * COUT + lane];
            int nch = nvox >> 6;
            for (int ch = 0; ch < nch; ++ch) {
                int idx = nbr[(size_t)k * n + st0 + ch * 64 + lane];
                unsigned long long m = __ballot(idx >= 0);
                while (m) {
                    int b = __builtin_ctzll(m);
                    m &= m - 1;
                    int src = __builtin_amdgcn_readlane(idx, b);
                    float t = rowdot(xh, src, wk);
                    atomicAdd(&acc[(ch * 64 + b) * LPAD + lane], t);
                }
            }
        }
        __syncthreads();

        // ---- flush: coalesced float4 stores, out written exactly once ----
        float4* out4 = (float4*)out;
        int ng = nvox * 16;                        // float4 count
#pragma unroll
        for (int jf = 0; jf < 6; ++jf) {
            int g = threadIdx.x + jf * 1024;
            if (g < ng) {
                int v  = g >> 4;
                int c4 = g & 15;
                float4 val = *(const float4*)&acc[v * LPAD + c4 * 4];
                out4[(size_t)st0 * 16 + g] = val;
            }
        }
        __syncthreads();
    }
}

extern "C" void kernel_launch(void* const* d_in, const int* in_sizes, int n_in,
                              void* d_out, int out_size, void* d_ws, size_t ws_size,
                              hipStream_t stream) {
    const float* feat  = (const float*)d_in[0];
    const float* gamma = (const float*)d_in[1];
    const float* beta  = (const float*)d_in[2];
    const float* W     = (const float*)d_in[3];
    const int*   nbr   = (const int*)d_in[4];
    float* out = (float*)d_out;
    float* ws  = (float*)d_ws;

    int n    = in_sizes[0] / CIN;                  // 400000
    int n4   = in_sizes[0] / 4;
    int nsub = (n + STILE - 1) / STILE;            // 1042
    float* xh   = ws + 160;
    int*   tick = (int*)(ws + 144);

    hipLaunchKernelGGL(k_zero,   dim3(1), dim3(256), 0, stream, ws);
    hipLaunchKernelGGL(k_reduce, dim3(512), dim3(256), 0, stream, feat, ws, n4);
    hipLaunchKernelGGL(k_final,  dim3(1), dim3(32), 0, stream, gamma, beta, ws, 1.0f / (float)n);
    hipLaunchKernelGGL(k_norm,   dim3(2048), dim3(256), 0, stream, feat, ws, xh, n4);
    hipLaunchKernelGGL(k_conv,   dim3(256), dim3(1024), 0, stream, xh, W, nbr, out, tick, n, nsub);
}

// Round 4
// 257.757 us; speedup vs baseline: 3.8772x; 1.3374x over previous
//
#include <hip/hip_runtime.h>
#include <hip/hip_bf16.h>

#define CIN  32
#define COUT 64
#define KCEN 13
#define FEPS 1e-5f

// ws float layout:
// [0,32) sums  [32,64) sumsq  [64,96) scale  [96,128) bias
// [160, 160+N*32) xhat f32 [N][32]

struct W8 { float4 w0, w1, w2, w3, w4, w5, w6, w7; };

#define PIN4(v) asm volatile("" : "+v"(v.x), "+v"(v.y), "+v"(v.z), "+v"(v.w))

// load the 32-float W column for offset k, lane = out channel; pinned in VGPRs
__device__ __forceinline__ W8 load_wcol(const float* __restrict__ W, int k, int lane) {
    const float* Wk = W + (size_t)k * (CIN * COUT) + lane;
    W8 r;
    r.w0 = make_float4(Wk[0 * 64], Wk[1 * 64], Wk[2 * 64], Wk[3 * 64]);
    r.w1 = make_float4(Wk[4 * 64], Wk[5 * 64], Wk[6 * 64], Wk[7 * 64]);
    r.w2 = make_float4(Wk[8 * 64], Wk[9 * 64], Wk[10 * 64], Wk[11 * 64]);
    r.w3 = make_float4(Wk[12 * 64], Wk[13 * 64], Wk[14 * 64], Wk[15 * 64]);
    r.w4 = make_float4(Wk[16 * 64], Wk[17 * 64], Wk[18 * 64], Wk[19 * 64]);
    r.w5 = make_float4(Wk[20 * 64], Wk[21 * 64], Wk[22 * 64], Wk[23 * 64]);
    r.w6 = make_float4(Wk[24 * 64], Wk[25 * 64], Wk[26 * 64], Wk[27 * 64]);
    r.w7 = make_float4(Wk[28 * 64], Wk[29 * 64], Wk[30 * 64], Wk[31 * 64]);
    PIN4(r.w0); PIN4(r.w1); PIN4(r.w2); PIN4(r.w3);
    PIN4(r.w4); PIN4(r.w5); PIN4(r.w6); PIN4(r.w7);
    return r;
}

#define FMA4(X, WV, a, b, c, d)                     \
    a = fmaf(X.x, WV.x, a); b = fmaf(X.y, WV.y, b); \
    c = fmaf(X.z, WV.z, c); d = fmaf(X.w, WV.w, d);

// two row-dots with all 16 loads issued before any FMA (MLP = 16 per wave)
__device__ __forceinline__ void dot2(const float4* __restrict__ ra,
                                     const float4* __restrict__ rb,
                                     W8 w, float& ta, float& tb) {
    float4 a0 = ra[0], a1 = ra[1], a2 = ra[2], a3 = ra[3];
    float4 a4 = ra[4], a5 = ra[5], a6 = ra[6], a7 = ra[7];
    float4 b0 = rb[0], b1 = rb[1], b2 = rb[2], b3 = rb[3];
    float4 b4 = rb[4], b5 = rb[5], b6 = rb[6], b7 = rb[7];
    float p0 = 0.f, p1 = 0.f, p2 = 0.f, p3 = 0.f;
    float q0 = 0.f, q1 = 0.f, q2 = 0.f, q3 = 0.f;
    FMA4(a0, w.w0, p0, p1, p2, p3) FMA4(b0, w.w0, q0, q1, q2, q3)
    FMA4(a1, w.w1, p0, p1, p2, p3) FMA4(b1, w.w1, q0, q1, q2, q3)
    FMA4(a2, w.w2, p0, p1, p2, p3) FMA4(b2, w.w2, q0, q1, q2, q3)
    FMA4(a3, w.w3, p0, p1, p2, p3) FMA4(b3, w.w3, q0, q1, q2, q3)
    FMA4(a4, w.w4, p0, p1, p2, p3) FMA4(b4, w.w4, q0, q1, q2, q3)
    FMA4(a5, w.w5, p0, p1, p2, p3) FMA4(b5, w.w5, q0, q1, q2, q3)
    FMA4(a6, w.w6, p0, p1, p2, p3) FMA4(b6, w.w6, q0, q1, q2, q3)
    FMA4(a7, w.w7, p0, p1, p2, p3) FMA4(b7, w.w7, q0, q1, q2, q3)
    ta = (p0 + p1) + (p2 + p3);
    tb = (q0 + q1) + (q2 + q3);
}

__device__ __forceinline__ float dot1(const float4* __restrict__ ra, W8 w) {
    float4 a0 = ra[0], a1 = ra[1], a2 = ra[2], a3 = ra[3];
    float4 a4 = ra[4], a5 = ra[5], a6 = ra[6], a7 = ra[7];
    float p0 = 0.f, p1 = 0.f, p2 = 0.f, p3 = 0.f;
    FMA4(a0, w.w0, p0, p1, p2, p3) FMA4(a1, w.w1, p0, p1, p2, p3)
    FMA4(a2, w.w2, p0, p1, p2, p3) FMA4(a3, w.w3, p0, p1, p2, p3)
    FMA4(a4, w.w4, p0, p1, p2, p3) FMA4(a5, w.w5, p0, p1, p2, p3)
    FMA4(a6, w.w6, p0, p1, p2, p3) FMA4(a7, w.w7, p0, p1, p2, p3)
    return (p0 + p1) + (p2 + p3);
}

__global__ void k_zero(float* __restrict__ ws) {
    if (threadIdx.x < 128) ws[threadIdx.x] = 0.f;
}

__global__ __launch_bounds__(256) void k_reduce(const float* __restrict__ f,
                                                float* __restrict__ ws, int n4) {
    const float4* f4 = (const float4*)f;
    int tid    = blockIdx.x * blockDim.x + threadIdx.x;
    int stride = gridDim.x * blockDim.x;          // multiple of 8
    float4 s = make_float4(0.f, 0.f, 0.f, 0.f);
    float4 q = make_float4(0.f, 0.f, 0.f, 0.f);
    for (int i = tid; i < n4; i += stride) {
        float4 v = f4[i];
        s.x += v.x; s.y += v.y; s.z += v.z; s.w += v.w;
        q.x = fmaf(v.x, v.x, q.x); q.y = fmaf(v.y, v.y, q.y);
        q.z = fmaf(v.z, v.z, q.z); q.w = fmaf(v.w, v.w, q.w);
    }
    __shared__ float ls[64];
    if (threadIdx.x < 64) ls[threadIdx.x] = 0.f;
    __syncthreads();
    int g = threadIdx.x & 7;
    atomicAdd(&ls[g * 4 + 0], s.x); atomicAdd(&ls[g * 4 + 1], s.y);
    atomicAdd(&ls[g * 4 + 2], s.z); atomicAdd(&ls[g * 4 + 3], s.w);
    atomicAdd(&ls[32 + g * 4 + 0], q.x); atomicAdd(&ls[32 + g * 4 + 1], q.y);
    atomicAdd(&ls[32 + g * 4 + 2], q.z); atomicAdd(&ls[32 + g * 4 + 3], q.w);
    __syncthreads();
    if (threadIdx.x < 64) atomicAdd(&ws[threadIdx.x], ls[threadIdx.x]);
}

__global__ void k_final(const float* __restrict__ gamma, const float* __restrict__ beta,
                        float* __restrict__ ws, float invN) {
    int c = threadIdx.x;                          // 32 threads
    float mean = ws[c] * invN;
    float var  = fmaf(-mean, mean, ws[32 + c] * invN);
    float sc   = gamma[c] * rsqrtf(var + FEPS);
    ws[64 + c] = sc;
    ws[96 + c] = fmaf(-mean, sc, beta[c]);
}

__global__ __launch_bounds__(256) void k_norm(const float* __restrict__ f,
                                              const float* __restrict__ ws,
                                              float* __restrict__ xh, int n4) {
    const float4* f4 = (const float4*)f;
    float4* o4 = (float4*)xh;
    int tid    = blockIdx.x * blockDim.x + threadIdx.x;
    int stride = gridDim.x * blockDim.x;          // multiple of 8
    int g = threadIdx.x & 7;
    float4 sc = ((const float4*)(ws + 64))[g];
    float4 bi = ((const float4*)(ws + 96))[g];
    for (int i = tid; i < n4; i += stride) {
        float4 v = f4[i];
        v.x = fmaxf(fmaf(v.x, sc.x, bi.x), 0.f);
        v.y = fmaxf(fmaf(v.y, sc.y, bi.y), 0.f);
        v.z = fmaxf(fmaf(v.z, sc.z, bi.z), 0.f);
        v.w = fmaxf(fmaf(v.w, sc.w, bi.w), 0.f);
        o4[i] = v;
    }
}

// Dense center pass (nbr[13] is the identity): 4 rows per iteration, affine
// addresses -> deep load pipeline. Plain stores double as out zero-init.
__global__ __launch_bounds__(256) void k_center(const float* __restrict__ xh,
                                                const float* __restrict__ W,
                                                float* __restrict__ out, int n) {
    int lane = threadIdx.x;                       // 0..63
    W8 w = load_wcol(W, KCEN, lane);
    int wid   = blockIdx.x * 4 + threadIdx.y;
    int waves = gridDim.x * 4;
    int nq = n >> 2;                              // n % 4 == 0
    for (int qi = wid; qi < nq; qi += waves) {
        int i = qi * 4;
        const float4* r0 = (const float4*)(xh + (size_t)(i + 0) * CIN);
        const float4* r1 = (const float4*)(xh + (size_t)(i + 1) * CIN);
        const float4* r2 = (const float4*)(xh + (size_t)(i + 2) * CIN);
        const float4* r3 = (const float4*)(xh + (size_t)(i + 3) * CIN);
        float t0, t1, t2, t3;
        dot2(r0, r1, w, t0, t1);
        dot2(r2, r3, w, t2, t3);
        out[(size_t)(i + 0) * COUT + lane] = t0;
        out[(size_t)(i + 1) * COUT + lane] = t1;
        out[(size_t)(i + 2) * COUT + lane] = t2;
        out[(size_t)(i + 3) * COUT + lane] = t3;
    }
}

// Sparse scatter, 26 non-center offsets. Fixes vs R1: (1) idx prefetched one
// chunk-iteration ahead (no serial load->ballot chain), (2) rowdots batched
// 2-deep with VGPR-pinned gather addresses, (3) W column pinned in VGPRs.
__global__ __launch_bounds__(256) void k_scatter(const float* __restrict__ xh,
                                                 const float* __restrict__ W,
                                                 const int* __restrict__ nbr,
                                                 float* __restrict__ out, int n) {
    int lane = threadIdx.x;
    int k = blockIdx.y; if (k >= KCEN) ++k;       // skip center
    W8 w = load_wcol(W, k, lane);

    const int* nk = nbr + (size_t)k * n;
    int wid   = blockIdx.x * 4 + threadIdx.y;
    int waves = gridDim.x * 4;
    int nch = n >> 6;                             // n % 64 == 0

    int ch = wid;
    if (ch >= nch) return;
    int idx = nk[ch * 64 + lane];
    while (ch < nch) {
        int chn = ch + waves;
        int idxn = -1;
        if (chn < nch) idxn = nk[chn * 64 + lane];   // prefetch next chunk
        unsigned long long m = __ballot(idx >= 0);
        int base = ch * 64;
        while (m) {
            int b0 = __builtin_ctzll(m); m &= m - 1;
            int s0 = __shfl(idx, b0);
            asm volatile("" : "+v"(s0));             // keep address in VGPR
            const float4* ra = (const float4*)(xh + (size_t)s0 * CIN);
            if (m) {
                int b1 = __builtin_ctzll(m); m &= m - 1;
                int s1 = __shfl(idx, b1);
                asm volatile("" : "+v"(s1));
                const float4* rb = (const float4*)(xh + (size_t)s1 * CIN);
                float t0, t1;
                dot2(ra, rb, w, t0, t1);
                unsafeAtomicAdd(&out[(size_t)(base + b0) * COUT + lane], t0);
                unsafeAtomicAdd(&out[(size_t)(base + b1) * COUT + lane], t1);
            } else {
                float t0 = dot1(ra, w);
                unsafeAtomicAdd(&out[(size_t)(base + b0) * COUT + lane], t0);
            }
        }
        idx = idxn;
        ch = chn;
    }
}

extern "C" void kernel_launch(void* const* d_in, const int* in_sizes, int n_in,
                              void* d_out, int out_size, void* d_ws, size_t ws_size,
                              hipStream_t stream) {
    const float* feat  = (const float*)d_in[0];
    const float* gamma = (const float*)d_in[1];
    const float* beta  = (const float*)d_in[2];
    const float* W     = (const float*)d_in[3];
    const int*   nbr   = (const int*)d_in[4];
    float* out = (float*)d_out;
    float* ws  = (float*)d_ws;

    int n  = in_sizes[0] / CIN;                   // 400000
    int n4 = in_sizes[0] / 4;
    float* xh = ws + 160;

    hipLaunchKernelGGL(k_zero,    dim3(1), dim3(128), 0, stream, ws);
    hipLaunchKernelGGL(k_reduce,  dim3(512), dim3(256), 0, stream, feat, ws, n4);
    hipLaunchKernelGGL(k_final,   dim3(1), dim3(32), 0, stream, gamma, beta, ws, 1.0f / (float)n);
    hipLaunchKernelGGL(k_norm,    dim3(2048), dim3(256), 0, stream, feat, ws, xh, n4);
    hipLaunchKernelGGL(k_center,  dim3(512), dim3(64, 4), 0, stream, xh, W, out, n);
    hipLaunchKernelGGL(k_scatter, dim3(64, 26), dim3(64, 4), 0, stream, xh, W, nbr, out, n);
}

// Round 5
// 169.467 us; speedup vs baseline: 5.8971x; 1.5210x over previous
//
#include <hip/hip_runtime.h>
#include <hip/hip_bf16.h>

#define CIN  32
#define COUT 64
#define KCEN 13
#define FEPS 1e-5f

// ws float layout:
// [0,32) sums  [32,64) sumsq  [64,96) scale  [96,128) bias
// [160, 160+N*32) xhat f32 [N][32]

#define FMA4(X, WV, a, b, c, d)                         \
    a = fmaf(X.x, WV[0], a); b = fmaf(X.y, WV[1], b);   \
    c = fmaf(X.z, WV[2], c); d = fmaf(X.w, WV[3], d);

// two row-dots, all 16 loads issued before the FMAs (MLP=16)
__device__ __forceinline__ void dot2(const float4* __restrict__ ra,
                                     const float4* __restrict__ rb,
                                     const float* __restrict__ w,
                                     float& ta, float& tb) {
    float4 a0 = ra[0], a1 = ra[1], a2 = ra[2], a3 = ra[3];
    float4 a4 = ra[4], a5 = ra[5], a6 = ra[6], a7 = ra[7];
    float4 b0 = rb[0], b1 = rb[1], b2 = rb[2], b3 = rb[3];
    float4 b4 = rb[4], b5 = rb[5], b6 = rb[6], b7 = rb[7];
    float p0 = 0.f, p1 = 0.f, p2 = 0.f, p3 = 0.f;
    float q0 = 0.f, q1 = 0.f, q2 = 0.f, q3 = 0.f;
    FMA4(a0, (w + 0), p0, p1, p2, p3)  FMA4(b0, (w + 0), q0, q1, q2, q3)
    FMA4(a1, (w + 4), p0, p1, p2, p3)  FMA4(b1, (w + 4), q0, q1, q2, q3)
    FMA4(a2, (w + 8), p0, p1, p2, p3)  FMA4(b2, (w + 8), q0, q1, q2, q3)
    FMA4(a3, (w + 12), p0, p1, p2, p3) FMA4(b3, (w + 12), q0, q1, q2, q3)
    FMA4(a4, (w + 16), p0, p1, p2, p3) FMA4(b4, (w + 16), q0, q1, q2, q3)
    FMA4(a5, (w + 20), p0, p1, p2, p3) FMA4(b5, (w + 20), q0, q1, q2, q3)
    FMA4(a6, (w + 24), p0, p1, p2, p3) FMA4(b6, (w + 24), q0, q1, q2, q3)
    FMA4(a7, (w + 28), p0, p1, p2, p3) FMA4(b7, (w + 28), q0, q1, q2, q3)
    ta = (p0 + p1) + (p2 + p3);
    tb = (q0 + q1) + (q2 + q3);
}

__device__ __forceinline__ float dot1(const float4* __restrict__ ra,
                                      const float* __restrict__ w) {
    float4 a0 = ra[0], a1 = ra[1], a2 = ra[2], a3 = ra[3];
    float4 a4 = ra[4], a5 = ra[5], a6 = ra[6], a7 = ra[7];
    float p0 = 0.f, p1 = 0.f, p2 = 0.f, p3 = 0.f;
    FMA4(a0, (w + 0), p0, p1, p2, p3)  FMA4(a1, (w + 4), p0, p1, p2, p3)
    FMA4(a2, (w + 8), p0, p1, p2, p3)  FMA4(a3, (w + 12), p0, p1, p2, p3)
    FMA4(a4, (w + 16), p0, p1, p2, p3) FMA4(a5, (w + 20), p0, p1, p2, p3)
    FMA4(a6, (w + 24), p0, p1, p2, p3) FMA4(a7, (w + 28), p0, p1, p2, p3)
    return (p0 + p1) + (p2 + p3);
}

__global__ void k_zero(float* __restrict__ ws) {
    if (threadIdx.x < 128) ws[threadIdx.x] = 0.f;
}

__global__ __launch_bounds__(256) void k_reduce(const float* __restrict__ f,
                                                float* __restrict__ ws, int n4) {
    const float4* f4 = (const float4*)f;
    int tid    = blockIdx.x * blockDim.x + threadIdx.x;
    int stride = gridDim.x * blockDim.x;          // multiple of 8
    float4 s = make_float4(0.f, 0.f, 0.f, 0.f);
    float4 q = make_float4(0.f, 0.f, 0.f, 0.f);
    for (int i = tid; i < n4; i += stride) {
        float4 v = f4[i];
        s.x += v.x; s.y += v.y; s.z += v.z; s.w += v.w;
        q.x = fmaf(v.x, v.x, q.x); q.y = fmaf(v.y, v.y, q.y);
        q.z = fmaf(v.z, v.z, q.z); q.w = fmaf(v.w, v.w, q.w);
    }
    __shared__ float ls[64];
    if (threadIdx.x < 64) ls[threadIdx.x] = 0.f;
    __syncthreads();
    int g = threadIdx.x & 7;
    atomicAdd(&ls[g * 4 + 0], s.x); atomicAdd(&ls[g * 4 + 1], s.y);
    atomicAdd(&ls[g * 4 + 2], s.z); atomicAdd(&ls[g * 4 + 3], s.w);
    atomicAdd(&ls[32 + g * 4 + 0], q.x); atomicAdd(&ls[32 + g * 4 + 1], q.y);
    atomicAdd(&ls[32 + g * 4 + 2], q.z); atomicAdd(&ls[32 + g * 4 + 3], q.w);
    __syncthreads();
    if (threadIdx.x < 64) atomicAdd(&ws[threadIdx.x], ls[threadIdx.x]);
}

__global__ void k_final(const float* __restrict__ gamma, const float* __restrict__ beta,
                        float* __restrict__ ws, float invN) {
    int c = threadIdx.x;                          // 32 threads
    float mean = ws[c] * invN;
    float var  = fmaf(-mean, mean, ws[32 + c] * invN);
    float sc   = gamma[c] * rsqrtf(var + FEPS);
    ws[64 + c] = sc;
    ws[96 + c] = fmaf(-mean, sc, beta[c]);
}

__global__ __launch_bounds__(256) void k_norm(const float* __restrict__ f,
                                              const float* __restrict__ ws,
                                              float* __restrict__ xh, int n4) {
    const float4* f4 = (const float4*)f;
    float4* o4 = (float4*)xh;
    int tid    = blockIdx.x * blockDim.x + threadIdx.x;
    int stride = gridDim.x * blockDim.x;          // multiple of 8
    int g = threadIdx.x & 7;
    float4 sc = ((const float4*)(ws + 64))[g];
    float4 bi = ((const float4*)(ws + 96))[g];
    for (int i = tid; i < n4; i += stride) {
        float4 v = f4[i];
        v.x = fmaxf(fmaf(v.x, sc.x, bi.x), 0.f);
        v.y = fmaxf(fmaf(v.y, sc.y, bi.y), 0.f);
        v.z = fmaxf(fmaf(v.z, sc.z, bi.z), 0.f);
        v.w = fmaxf(fmaf(v.w, sc.w, bi.w), 0.f);
        o4[i] = v;
    }
}

// Dense center pass: one 64-row tile per block. Coalesced float4 stage to
// LDS, then each wave computes 16 rows via uniform (broadcast) LDS reads.
// Plain stores double as the zero-init of out.
__global__ __launch_bounds__(256, 4) void k_center(const float* __restrict__ xh,
                                                   const float* __restrict__ W,
                                                   float* __restrict__ out, int n) {
    __shared__ float xs[64 * CIN];                 // 8 KB
    int lane = threadIdx.x & 63;
    int wv   = threadIdx.x >> 6;                   // wave 0..3

    float w[CIN];
#pragma unroll
    for (int c = 0; c < CIN; ++c) w[c] = W[(size_t)KCEN * (CIN * COUT) + c * COUT + lane];

    int r0 = blockIdx.x * 64;                      // grid = n/64 (n % 64 == 0)
    const float4* src = (const float4*)(xh + (size_t)r0 * CIN);
    float4* dst = (float4*)xs;
    dst[threadIdx.x]       = src[threadIdx.x];
    dst[threadIdx.x + 256] = src[threadIdx.x + 256];
    __syncthreads();

#pragma unroll
    for (int rr = 0; rr < 16; rr += 2) {
        int r = wv * 16 + rr;
        const float4* ra = (const float4*)&xs[(r + 0) * CIN];
        const float4* rb = (const float4*)&xs[(r + 1) * CIN];
        float t0, t1;
        dot2(ra, rb, w, t0, t1);
        out[(size_t)(r0 + r + 0) * COUT + lane] = t0;
        out[(size_t)(r0 + r + 1) * COUT + lane] = t1;
    }
}

// Sparse scatter, 26 non-center offsets. Ballot-peel with chunk-ahead idx
// prefetch and 2-deep batched row gathers (registers now budgeted for it).
__global__ __launch_bounds__(256, 4) void k_scatter(const float* __restrict__ xh,
                                                    const float* __restrict__ W,
                                                    const int* __restrict__ nbr,
                                                    float* __restrict__ out, int n) {
    int lane = threadIdx.x;
    int k = blockIdx.y; if (k >= KCEN) ++k;       // skip center
    float w[CIN];
#pragma unroll
    for (int c = 0; c < CIN; ++c) w[c] = W[(size_t)k * (CIN * COUT) + c * COUT + lane];

    const int* nk = nbr + (size_t)k * n;
    int wid   = blockIdx.x * 4 + threadIdx.y;
    int waves = gridDim.x * 4;
    int nch = n >> 6;                             // n % 64 == 0

    int ch = wid;
    if (ch >= nch) return;
    int idx = nk[ch * 64 + lane];
    while (ch < nch) {
        int chn = ch + waves;
        int idxn = -1;
        if (chn < nch) idxn = nk[chn * 64 + lane];   // prefetch next chunk
        unsigned long long m = __ballot(idx >= 0);
        int base = ch * 64;
        while (m) {
            int b0 = __builtin_ctzll(m); m &= m - 1;
            int s0 = __shfl(idx, b0);
            const float4* ra = (const float4*)(xh + (size_t)s0 * CIN);
            if (m) {
                int b1 = __builtin_ctzll(m); m &= m - 1;
                int s1 = __shfl(idx, b1);
                const float4* rb = (const float4*)(xh + (size_t)s1 * CIN);
                float t0, t1;
                dot2(ra, rb, w, t0, t1);
                unsafeAtomicAdd(&out[(size_t)(base + b0) * COUT + lane], t0);
                unsafeAtomicAdd(&out[(size_t)(base + b1) * COUT + lane], t1);
            } else {
                float t0 = dot1(ra, w);
                unsafeAtomicAdd(&out[(size_t)(base + b0) * COUT + lane], t0);
            }
        }
        idx = idxn;
        ch = chn;
    }
}

extern "C" void kernel_launch(void* const* d_in, const int* in_sizes, int n_in,
                              void* d_out, int out_size, void* d_ws, size_t ws_size,
                              hipStream_t stream) {
    const float* feat  = (const float*)d_in[0];
    const float* gamma = (const float*)d_in[1];
    const float* beta  = (const float*)d_in[2];
    const float* W     = (const float*)d_in[3];
    const int*   nbr   = (const int*)d_in[4];
    float* out = (float*)d_out;
    float* ws  = (float*)d_ws;

    int n  = in_sizes[0] / CIN;                   // 400000
    int n4 = in_sizes[0] / 4;
    float* xh = ws + 160;
    int ntile = n >> 6;                           // 6250

    hipLaunchKernelGGL(k_zero,    dim3(1), dim3(128), 0, stream, ws);
    hipLaunchKernelGGL(k_reduce,  dim3(512), dim3(256), 0, stream, feat, ws, n4);
    hipLaunchKernelGGL(k_final,   dim3(1), dim3(32), 0, stream, gamma, beta, ws, 1.0f / (float)n);
    hipLaunchKernelGGL(k_norm,    dim3(2048), dim3(256), 0, stream, feat, ws, xh, n4);
    hipLaunchKernelGGL(k_center,  dim3(ntile), dim3(256), 0, stream, xh, W, out, n);
    hipLaunchKernelGGL(k_scatter, dim3(64, 26), dim3(64, 4), 0, stream, xh, W, nbr, out, n);
}